// Round 1
// baseline (257.932 us; speedup 1.0000x reference)
//
#include <hip/hip_runtime.h>

// MultiHeadAttention: N=4, S=T=2048, E=512, H=8, HD=64. fp32 in/out, bf16 MFMA compute.
// Pipeline: cast->bf16 | 3x GEMM (QKV proj) | flash attention (causal) | GEMM (out proj).

#define DEV __device__ __forceinline__

typedef unsigned short u16;
typedef __bf16 bf16x8 __attribute__((ext_vector_type(8)));
typedef float f32x4 __attribute__((ext_vector_type(4)));

#define MFMA_BF16(A, B, C) __builtin_amdgcn_mfma_f32_16x16x32_bf16(A, B, C, 0, 0, 0)

DEV u16 f2bf(float f) {  // RNE float->bf16 (NaN not expected in this data)
  unsigned int u = __builtin_bit_cast(unsigned int, f);
  u += 0x7fffu + ((u >> 16) & 1u);
  return (u16)(u >> 16);
}

// async global->LDS, 16B per lane. LDS dst must be wave-uniform base + lane*16.
DEV void cp16(void* l, const void* g) {
  __builtin_amdgcn_global_load_lds(
      (const __attribute__((address_space(1))) unsigned int*)g,
      (__attribute__((address_space(3))) unsigned int*)l, 16, 0, 0);
}

__global__ __launch_bounds__(256) void cast_f32_bf16(const float* __restrict__ src,
                                                     u16* __restrict__ dst, int n4) {
  int i = blockIdx.x * 256 + threadIdx.x;
  if (i >= n4) return;
  float4 f = ((const float4*)src)[i];
  ushort4 o;
  o.x = f2bf(f.x); o.y = f2bf(f.y); o.z = f2bf(f.z); o.w = f2bf(f.w);
  ((ushort4*)dst)[i] = o;
}

// C[m,n] = sum_k A[m,k]*W[n,k] + bias[n].  A: 8192x512 bf16, W: 512x512 bf16 (B^T layout).
// m97 structure: 128x128 tile, BK=32, 4 waves (2x2 of 64x64), global_load_lds staging.
template <int OUT_BF16>
__global__ __launch_bounds__(256) void gemm_bias(const u16* __restrict__ A,
                                                 const u16* __restrict__ W,
                                                 const float* __restrict__ bias,
                                                 void* __restrict__ Cv) {
  __shared__ u16 As[128 * 32];
  __shared__ u16 Bs[128 * 32];
  const int tid = threadIdx.x;
  const int lane = tid & 63, wid = tid >> 6;
  const int wm = wid & 1, wn = wid >> 1;
  const int l15 = lane & 15, l4 = lane >> 4;
  const int m0 = blockIdx.y * 128, n0 = blockIdx.x * 128;

  f32x4 acc[4][4] = {};

  for (int kt = 0; kt < 512; kt += 32) {
    __syncthreads();
#pragma unroll
    for (int i = 0; i < 2; ++i) {  // 512 chunks of 16B per tile-pair half
      int c = tid + 256 * i;
      int row = c >> 2, kc = (c & 3) * 8;
      cp16(&As[c * 8], A + (m0 + row) * 512 + kt + kc);
      cp16(&Bs[c * 8], W + (n0 + row) * 512 + kt + kc);
    }
    __syncthreads();
    bf16x8 af[4], bfr[4];
#pragma unroll
    for (int f = 0; f < 4; ++f) {
      af[f]  = *(const bf16x8*)&As[(wm * 64 + f * 16 + l15) * 32 + l4 * 8];
      bfr[f] = *(const bf16x8*)&Bs[(wn * 64 + f * 16 + l15) * 32 + l4 * 8];
    }
#pragma unroll
    for (int fm = 0; fm < 4; ++fm)
#pragma unroll
      for (int fn = 0; fn < 4; ++fn)
        acc[fm][fn] = MFMA_BF16(af[fm], bfr[fn], acc[fm][fn]);
  }

#pragma unroll
  for (int fn = 0; fn < 4; ++fn) {
    int col = n0 + wn * 64 + fn * 16 + l15;
    float bv = bias[col];
#pragma unroll
    for (int fm = 0; fm < 4; ++fm) {
      int rowb = m0 + wm * 64 + fm * 16 + l4 * 4;
#pragma unroll
      for (int r = 0; r < 4; ++r) {
        float v = acc[fm][fn][r] + bv;  // C/D: row=(lane>>4)*4+r, col=lane&15  [m89]
        if (OUT_BF16)
          ((u16*)Cv)[(rowb + r) * 512 + col] = f2bf(v);
        else
          ((float*)Cv)[(rowb + r) * 512 + col] = v;
      }
    }
  }
}

// Flash attention, causal. q/k/v bf16, layout [n][s][h*64+d] (row stride E=512).
// Block: 256 thr (4 waves), one (n,h); processes paired Q-tiles qt and 31-qt (64 rows each)
// so every block does exactly 17 K-tile steps. K-tile = 128 rows.
// Wave w owns Q rows [w*16, w*16+16). LDS chunk layouts XOR-swizzled for b128 reads.
__global__ __launch_bounds__(256) void attn_kernel(const u16* __restrict__ Qg,
                                                   const u16* __restrict__ Kg,
                                                   const u16* __restrict__ Vg,
                                                   u16* __restrict__ Yg) {
  __shared__ u16 Qs[64 * 64];     // [m][d], chunk-swizzled: dgrp^(m&7)
  __shared__ u16 KPs[64 * 136];   // union: K tile [t(128)][d(64)] swizzled | P [m(64)][t(128)] stride 136
  __shared__ u16 Vts[64 * 128];   // V^T [d(64)][t(128)], chunk-swizzled: tgrp^(d&15)

  const int bid = blockIdx.x;
  const int pair = bid & 15, h = (bid >> 4) & 7, n = bid >> 7;
  const int tid = threadIdx.x, lane = tid & 63, w = tid >> 6;
  const int l15 = lane & 15, l4 = lane >> 4;

  const u16* Qb = Qg + n * 2048 * 512 + h * 64;
  const u16* Kb = Kg + n * 2048 * 512 + h * 64;
  const u16* Vb = Vg + n * 2048 * 512 + h * 64;

  for (int qi = 0; qi < 2; ++qi) {
    const int qt = (qi == 0) ? pair : 31 - pair;
    const int s0 = qt * 64;
    __syncthreads();  // all prior reads of Qs done
#pragma unroll
    for (int i = 0; i < 2; ++i) {  // stage Q tile: 512 chunks
      int c = tid + 256 * i;
      int row = c >> 3, dg = (c & 7) ^ (row & 7);
      cp16(&Qs[c * 8], Qb + (s0 + row) * 512 + dg * 8);
    }

    f32x4 accO[4] = {};
    float mrow[4], lrow[4];
#pragma unroll
    for (int r = 0; r < 4; ++r) { mrow[r] = -1e30f; lrow[r] = 0.f; }

    const int ntiles = (s0 >> 7) + 1;
    for (int it = 0; it < ntiles; ++it) {
      const int t0 = it * 128;
      __syncthreads();  // previous tile's PV reads of KPs/Vts done
#pragma unroll
      for (int i = 0; i < 4; ++i) {  // stage K tile: 1024 chunks
        int c = tid + 256 * i;
        int t = c >> 3, dg = (c & 7) ^ (t & 7);
        cp16(&KPs[c * 8], Kb + (t0 + t) * 512 + dg * 8);
      }
#pragma unroll
      for (int i = 0; i < 4; ++i) {  // stage V transposed (scalar writes)
        int c = tid + 256 * i;
        int t = c & 127, dgrp = c >> 7;
        uint4 vv = *(const uint4*)(Vb + (t0 + t) * 512 + dgrp * 8);
        unsigned int ua[4] = {vv.x, vv.y, vv.z, vv.w};
#pragma unroll
        for (int j = 0; j < 8; ++j) {
          int d = dgrp * 8 + j;
          Vts[d * 128 + (((t >> 3) ^ (d & 15)) * 8) + (t & 7)] = (u16)(ua[j >> 1] >> ((j & 1) * 16));
        }
      }
      __syncthreads();  // K, Vt (and Q on first tile) ready

      // ---- S = Q K^T for this wave's 16 rows x 128 cols ----
      f32x4 accS[8] = {};
      const int qr = w * 16 + l15;
#pragma unroll
      for (int ks = 0; ks < 2; ++ks) {
        bf16x8 aq = *(const bf16x8*)&Qs[qr * 64 + (((ks * 4 + l4) ^ (qr & 7)) * 8)];
#pragma unroll
        for (int fn = 0; fn < 8; ++fn) {
          int tr = fn * 16 + l15;
          bf16x8 bk = *(const bf16x8*)&KPs[tr * 64 + (((ks * 4 + l4) ^ (tr & 7)) * 8)];
          accS[fn] = MFMA_BF16(aq, bk, accS[fn]);
        }
      }

      // ---- online softmax (rows = l4*4+r of this wave's strip) ----
      const bool diag = (t0 + 128 > s0);
      float rmax[4];
#pragma unroll
      for (int r = 0; r < 4; ++r) rmax[r] = -1e30f;
#pragma unroll
      for (int fn = 0; fn < 8; ++fn) {
        int tcol = t0 + fn * 16 + l15;
#pragma unroll
        for (int r = 0; r < 4; ++r) {
          float v = accS[fn][r] * 0.125f;  // 1/sqrt(64)
          if (diag && tcol > s0 + w * 16 + l4 * 4 + r) v = -1e30f;
          accS[fn][r] = v;
          rmax[r] = fmaxf(rmax[r], v);
        }
      }
#pragma unroll
      for (int m = 1; m < 16; m <<= 1)
#pragma unroll
        for (int r = 0; r < 4; ++r) rmax[r] = fmaxf(rmax[r], __shfl_xor(rmax[r], m));
      float alpha[4], rsum[4];
#pragma unroll
      for (int r = 0; r < 4; ++r) {
        float mn = fmaxf(mrow[r], rmax[r]);
        alpha[r] = __expf(mrow[r] - mn);
        mrow[r] = mn;
        rsum[r] = 0.f;
      }
#pragma unroll
      for (int fn = 0; fn < 8; ++fn)
#pragma unroll
        for (int r = 0; r < 4; ++r) {
          float p = __expf(accS[fn][r] - mrow[r]);
          accS[fn][r] = p;
          rsum[r] += p;
        }
#pragma unroll
      for (int m = 1; m < 16; m <<= 1)
#pragma unroll
        for (int r = 0; r < 4; ++r) rsum[r] += __shfl_xor(rsum[r], m);
#pragma unroll
      for (int r = 0; r < 4; ++r) lrow[r] = lrow[r] * alpha[r] + rsum[r];
#pragma unroll
      for (int fd = 0; fd < 4; ++fd)
#pragma unroll
        for (int r = 0; r < 4; ++r) accO[fd][r] *= alpha[r];

      __syncthreads();  // ALL waves done reading K before P overwrites it

      // ---- P (C-layout) -> LDS [m][t] stride 136, own strip only ----
#pragma unroll
      for (int fn = 0; fn < 8; ++fn)
#pragma unroll
        for (int r = 0; r < 4; ++r)
          KPs[(w * 16 + l4 * 4 + r) * 136 + fn * 16 + l15] = f2bf(accS[fn][r]);
      // intra-wave ds ordering makes P visible to our own A-frag reads (own strip only)

      // ---- O += P V ----
#pragma unroll
      for (int ks = 0; ks < 4; ++ks) {
        bf16x8 ap = *(const bf16x8*)&KPs[(w * 16 + l15) * 136 + ks * 32 + l4 * 8];
#pragma unroll
        for (int fd = 0; fd < 4; ++fd) {
          int d = fd * 16 + l15;
          bf16x8 bv = *(const bf16x8*)&Vts[d * 128 + (((ks * 4 + l4) ^ (d & 15)) * 8)];
          accO[fd] = MFMA_BF16(ap, bv, accO[fd]);
        }
      }
    }

    // ---- epilogue: y[s][h*64+d] = O/l ----
#pragma unroll
    for (int fd = 0; fd < 4; ++fd)
#pragma unroll
      for (int r = 0; r < 4; ++r) {
        int row = s0 + w * 16 + l4 * 4 + r;
        int col = h * 64 + fd * 16 + l15;
        Yg[(n * 2048 + row) * 512 + col] = f2bf(accO[fd][r] / lrow[r]);
      }
  }
}

extern "C" void kernel_launch(void* const* d_in, const int* in_sizes, int n_in,
                              void* d_out, int out_size, void* d_ws, size_t ws_size,
                              hipStream_t stream) {
  (void)in_sizes; (void)n_in; (void)out_size; (void)ws_size;
  const float* query = (const float*)d_in[0];
  const float* key_  = (const float*)d_in[1];
  const float* value = (const float*)d_in[2];
  // d_in[3] = attn_mask (tril) — causal, applied structurally in attn_kernel
  const float* Wq = (const float*)d_in[4];
  const float* bq = (const float*)d_in[5];
  const float* Wk = (const float*)d_in[6];
  const float* bk = (const float*)d_in[7];
  const float* Wv = (const float*)d_in[8];
  const float* bv = (const float*)d_in[9];
  const float* Wp = (const float*)d_in[10];
  const float* bp = (const float*)d_in[11];

  char* ws = (char*)d_ws;  // ~50 MB used
  u16* qx  = (u16*)(ws);                // 8 MB (reused as y after q-proj consumes it)
  u16* kx  = (u16*)(ws + 8388608);      // 8 MB
  u16* vx  = (u16*)(ws + 16777216);     // 8 MB
  u16* wqx = (u16*)(ws + 25165824);     // 512 KB each
  u16* wkx = (u16*)(ws + 25690112);
  u16* wvx = (u16*)(ws + 26214400);
  u16* wpx = (u16*)(ws + 26738688);
  u16* qp  = (u16*)(ws + 27262976);     // 8 MB
  u16* kp  = (u16*)(ws + 35651584);     // 8 MB
  u16* vp  = (u16*)(ws + 44040192);     // 8 MB
  u16* y   = qx;

  cast_f32_bf16<<<4096, 256, 0, stream>>>(query, qx, 1048576);
  cast_f32_bf16<<<4096, 256, 0, stream>>>(key_,  kx, 1048576);
  cast_f32_bf16<<<4096, 256, 0, stream>>>(value, vx, 1048576);
  cast_f32_bf16<<<256, 256, 0, stream>>>(Wq, wqx, 65536);
  cast_f32_bf16<<<256, 256, 0, stream>>>(Wk, wkx, 65536);
  cast_f32_bf16<<<256, 256, 0, stream>>>(Wv, wvx, 65536);
  cast_f32_bf16<<<256, 256, 0, stream>>>(Wp, wpx, 65536);

  dim3 gg(4, 64);
  gemm_bias<1><<<gg, 256, 0, stream>>>(qx, wqx, bq, (void*)qp);
  gemm_bias<1><<<gg, 256, 0, stream>>>(kx, wkx, bk, (void*)kp);
  gemm_bias<1><<<gg, 256, 0, stream>>>(vx, wvx, bv, (void*)vp);

  attn_kernel<<<512, 256, 0, stream>>>(qp, kp, vp, y);

  gemm_bias<0><<<gg, 256, 0, stream>>>(y, wpx, bp, d_out);
}

// Round 2
// 209.477 us; speedup vs baseline: 1.2313x; 1.2313x over previous
//
#include <hip/hip_runtime.h>

// MultiHeadAttention: N=4, S=T=2048, E=512, H=8, HD=64. fp32 in/out, bf16 MFMA compute.
// R2: S^T-formulation flash attention (P^T lands write-friendly), pre-transposed V,
// fused QKV GEMM, exp2-domain softmax, fused casts. 6 dispatches total.

#define DEV __device__ __forceinline__

typedef unsigned short u16;
typedef unsigned int u32;
typedef __bf16 bf16x8 __attribute__((ext_vector_type(8)));
typedef float f32x4 __attribute__((ext_vector_type(4)));

#define MFMA_BF16(A, B, C) __builtin_amdgcn_mfma_f32_16x16x32_bf16(A, B, C, 0, 0, 0)

DEV u16 f2bf(float f) {  // RNE
  u32 u = __builtin_bit_cast(u32, f);
  u += 0x7fffu + ((u >> 16) & 1u);
  return (u16)(u >> 16);
}
DEV u16 f2bf_ru(float f) {  // round-half-up, for non-negative values (P matrix)
  u32 u = __builtin_bit_cast(u32, f);
  return (u16)((u + 0x8000u) >> 16);
}

// async global->LDS, 16B per lane. LDS dst must be lane-contiguous (wave-uniform base + lane*16).
DEV void cp16(void* l, const void* g) {
  __builtin_amdgcn_global_load_lds(
      (const __attribute__((address_space(1))) u32*)g,
      (__attribute__((address_space(3))) u32*)l, 16, 0, 0);
}

// ---------------- casts ----------------
__global__ __launch_bounds__(256) void cast3(const float* __restrict__ q,
                                             const float* __restrict__ k,
                                             const float* __restrict__ v,
                                             u16* qo, u16* ko, u16* vo) {
  const float* s = (blockIdx.y == 0) ? q : (blockIdx.y == 1) ? k : v;
  u16* d = (blockIdx.y == 0) ? qo : (blockIdx.y == 1) ? ko : vo;
  int i = blockIdx.x * 256 + threadIdx.x;  // grid.x*256 == elem4 count exactly
  float4 f = ((const float4*)s)[i];
  ushort4 o;
  o.x = f2bf(f.x); o.y = f2bf(f.y); o.z = f2bf(f.z); o.w = f2bf(f.w);
  ((ushort4*)d)[i] = o;
}

__global__ __launch_bounds__(256) void cast4(const float* __restrict__ a,
                                             const float* __restrict__ b,
                                             const float* __restrict__ c,
                                             const float* __restrict__ d2,
                                             u16* ao, u16* bo, u16* co, u16* do_) {
  int y = blockIdx.y;
  const float* s = (y == 0) ? a : (y == 1) ? b : (y == 2) ? c : d2;
  u16* d = (y == 0) ? ao : (y == 1) ? bo : (y == 2) ? co : do_;
  int i = blockIdx.x * 256 + threadIdx.x;
  float4 f = ((const float4*)s)[i];
  ushort4 o;
  o.x = f2bf(f.x); o.y = f2bf(f.y); o.z = f2bf(f.z); o.w = f2bf(f.w);
  ((ushort4*)d)[i] = o;
}

// ---------------- GEMM core: C[m,n] = sum_k A[m,k]*W[n,k] ----------------
// 128x128 tile, BK=32, 4 waves (2x2 of 64x64), global_load_lds width-16 staging.
DEV void gemm_loop(const u16* __restrict__ A, const u16* __restrict__ W,
                   u16* As, u16* Bs, int m0, int n0, int tid, f32x4 acc[4][4]) {
  const int lane = tid & 63, wid = tid >> 6;
  const int wm = wid & 1, wn = wid >> 1;
  const int l15 = lane & 15, l4 = lane >> 4;
  for (int kt = 0; kt < 512; kt += 32) {
    __syncthreads();
#pragma unroll
    for (int i = 0; i < 2; ++i) {
      int c = tid + 256 * i;
      int row = c >> 2, kc = (c & 3) * 8;
      cp16(&As[c * 8], A + (m0 + row) * 512 + kt + kc);
      cp16(&Bs[c * 8], W + (n0 + row) * 512 + kt + kc);
    }
    __syncthreads();
    bf16x8 af[4], bfr[4];
#pragma unroll
    for (int f = 0; f < 4; ++f) {
      af[f]  = *(const bf16x8*)&As[(wm * 64 + f * 16 + l15) * 32 + l4 * 8];
      bfr[f] = *(const bf16x8*)&Bs[(wn * 64 + f * 16 + l15) * 32 + l4 * 8];
    }
#pragma unroll
    for (int fm = 0; fm < 4; ++fm)
#pragma unroll
      for (int fn = 0; fn < 4; ++fn)
        acc[fm][fn] = MFMA_BF16(af[fm], bfr[fn], acc[fm][fn]);
  }
}

// Fused QKV projection: grid (12, 64); blockIdx.x>>2 selects Q/K/V problem.
__global__ __launch_bounds__(256) void gemm_qkv(
    const u16* __restrict__ qx, const u16* __restrict__ kx, const u16* __restrict__ vx,
    const u16* __restrict__ wq, const u16* __restrict__ wk, const u16* __restrict__ wv,
    const float* __restrict__ bq, const float* __restrict__ bk, const float* __restrict__ bv,
    u16* qp, u16* kp, u16* vp) {
  __shared__ u16 As[128 * 32];
  __shared__ u16 Bs[128 * 32];
  const int wsel = blockIdx.x >> 2;
  const u16* A = (wsel == 0) ? qx : (wsel == 1) ? kx : vx;
  const u16* W = (wsel == 0) ? wq : (wsel == 1) ? wk : wv;
  const float* bias = (wsel == 0) ? bq : (wsel == 1) ? bk : bv;
  u16* C = (wsel == 0) ? qp : (wsel == 1) ? kp : vp;
  const int n0 = (blockIdx.x & 3) * 128, m0 = blockIdx.y * 128;
  const int tid = threadIdx.x, lane = tid & 63, wid = tid >> 6;
  const int wm = wid & 1, wn = wid >> 1;
  const int l15 = lane & 15, l4 = lane >> 4;

  f32x4 acc[4][4] = {};
  gemm_loop(A, W, As, Bs, m0, n0, tid, acc);

#pragma unroll
  for (int fn = 0; fn < 4; ++fn) {
    int col = n0 + wn * 64 + fn * 16 + l15;
    float bvv = bias[col];
#pragma unroll
    for (int fm = 0; fm < 4; ++fm) {
      int rowb = m0 + wm * 64 + fm * 16 + l4 * 4;
#pragma unroll
      for (int r = 0; r < 4; ++r)
        C[(rowb + r) * 512 + col] = f2bf(acc[fm][fn][r] + bvv);
    }
  }
}

// Final projection: fp32 out.
__global__ __launch_bounds__(256) void gemm_out(const u16* __restrict__ A,
                                                const u16* __restrict__ W,
                                                const float* __restrict__ bias,
                                                float* __restrict__ C) {
  __shared__ u16 As[128 * 32];
  __shared__ u16 Bs[128 * 32];
  const int n0 = blockIdx.x * 128, m0 = blockIdx.y * 128;
  const int tid = threadIdx.x, lane = tid & 63, wid = tid >> 6;
  const int wm = wid & 1, wn = wid >> 1;
  const int l15 = lane & 15, l4 = lane >> 4;

  f32x4 acc[4][4] = {};
  gemm_loop(A, W, As, Bs, m0, n0, tid, acc);

#pragma unroll
  for (int fn = 0; fn < 4; ++fn) {
    int col = n0 + wn * 64 + fn * 16 + l15;
    float bvv = bias[col];
#pragma unroll
    for (int fm = 0; fm < 4; ++fm) {
      int rowb = m0 + wm * 64 + fm * 16 + l4 * 4;
#pragma unroll
      for (int r = 0; r < 4; ++r)
        C[(rowb + r) * 512 + col] = acc[fm][fn][r] + bvv;
    }
  }
}

// ---------------- V transpose: vp[n][t][h*64+d] -> vt[nh*64+d][t] ----------------
__global__ __launch_bounds__(256) void transpose_v(const u16* __restrict__ vp,
                                                   u16* __restrict__ vt) {
  __shared__ u16 L[64 * 72];  // 64x64 tile, stride 72 breaks bank alignment
  const int bid = blockIdx.x;  // 1024 = 32 t-tiles x 32 nh
  const int nh = bid & 31, tt = bid >> 5;
  const int n = nh >> 3, h = nh & 7;
  const u16* src = vp + (n * 2048 + tt * 64) * 512 + h * 64;
  const int tid = threadIdx.x;
#pragma unroll
  for (int i = 0; i < 2; ++i) {
    int c = tid + 256 * i;
    int row = c >> 3, dg = c & 7;
    uint4 x = *(const uint4*)(src + row * 512 + dg * 8);
    *(uint4*)&L[row * 72 + dg * 8] = x;  // (row*72+dg*8)*2 is 16B-aligned (144=9*16)
  }
  __syncthreads();
  u16* dst = vt + nh * 64 * 2048 + tt * 64;
#pragma unroll
  for (int i = 0; i < 2; ++i) {
    int c = tid + 256 * i;
    int d = c >> 3, tg = c & 7;
    u16 e[8];
#pragma unroll
    for (int j = 0; j < 8; ++j) e[j] = L[(tg * 8 + j) * 72 + d];
    uint4 o;
    o.x = (u32)e[0] | ((u32)e[1] << 16);
    o.y = (u32)e[2] | ((u32)e[3] << 16);
    o.z = (u32)e[4] | ((u32)e[5] << 16);
    o.w = (u32)e[6] | ((u32)e[7] << 16);
    *(uint4*)(dst + d * 2048 + tg * 8) = o;
  }
}

// ---------------- Flash attention, causal, S^T formulation ----------------
// grid 1024 = 32 q-tiles (64 rows) x 32 nh; heavy q-tiles dispatched first.
// Per tile-step: S^T = K*Q^T (C/D rows = t), softmax over t per column m=l15,
// P^T stored [m][t] via b64 writes, O += P*V with pre-transposed V staged via cp16.
__global__ __launch_bounds__(256) void attn_kernel(const u16* __restrict__ Qg,
                                                   const u16* __restrict__ Kg,
                                                   const u16* __restrict__ Vt,
                                                   u16* __restrict__ Yg) {
  __shared__ u16 Qs[64 * 64];    // Q tile [m][d], source-swizzled chunks
  __shared__ u16 KP[64 * 136];   // union: K tile 128x64 (16 KB) | P^T [m=64][t=128] stride 136
  __shared__ u16 Vts[64 * 128];  // V^T tile [d][t], source-swizzled chunks

  const int bid = blockIdx.x;
  const int nh = bid & 31;
  const int qt = 31 - (bid >> 5);  // heavy (long) q-tiles first
  const int n = nh >> 3, h = nh & 7;
  const int tid = threadIdx.x, lane = tid & 63, w = tid >> 6;
  const int l15 = lane & 15, l4 = lane >> 4;
  const int s0 = qt * 64;

  const u16* Qb = Qg + (n * 2048 + s0) * 512 + h * 64;
  const u16* Kb = Kg + n * 2048 * 512 + h * 64;
  const u16* Vb = Vt + nh * 64 * 2048;

  // stage Q tile once
#pragma unroll
  for (int i = 0; i < 2; ++i) {
    int c = tid + 256 * i;
    int row = c >> 3, dg = (c & 7) ^ (row & 7);
    cp16(&Qs[c * 8], Qb + row * 512 + dg * 8);
  }
  __syncthreads();
  const int qr = w * 16 + l15;
  bf16x8 qf0 = *(const bf16x8*)&Qs[qr * 64 + ((l4 ^ (qr & 7)) * 8)];
  bf16x8 qf1 = *(const bf16x8*)&Qs[qr * 64 + (((4 + l4) ^ (qr & 7)) * 8)];

  f32x4 accO[4] = {};
  float mrow = -1e30f, lrow = 0.f;      // softmax state for column m = l15 (s = s0+w*16+l15)
  const int sgl = s0 + w * 16 + l15;

  const int ntiles = (qt >> 1) + 1;
  for (int it = 0; it < ntiles; ++it) {
    const int t0 = it * 128;
    __syncthreads();  // prior PV reads of KP/Vts complete
#pragma unroll
    for (int i = 0; i < 4; ++i) {  // K tile: 1024 chunks
      int c = tid + 256 * i;
      int t = c >> 3, dg = (c & 7) ^ (t & 7);
      cp16(&KP[c * 8], Kb + (t0 + t) * 512 + dg * 8);
    }
#pragma unroll
    for (int i = 0; i < 4; ++i) {  // V^T tile: 1024 chunks (pre-transposed global)
      int c = tid + 256 * i;
      int d = c >> 4, tgs = c & 15;
      cp16(&Vts[c * 8], Vb + d * 2048 + t0 + ((tgs ^ (d & 15)) * 8));
    }
    __syncthreads();

    // ---- S^T = K Q^T : 8 frags along t (rows), cols m = l15 ----
    f32x4 st[8];
#pragma unroll
    for (int fn = 0; fn < 8; ++fn) {
      int tr = fn * 16 + l15;
      bf16x8 k0 = *(const bf16x8*)&KP[tr * 64 + ((l4 ^ (tr & 7)) * 8)];
      bf16x8 k1 = *(const bf16x8*)&KP[tr * 64 + (((4 + l4) ^ (tr & 7)) * 8)];
      f32x4 a = {};
      a = MFMA_BF16(k0, qf0, a);
      st[fn] = MFMA_BF16(k1, qf1, a);
    }

    // ---- online softmax in exp2 domain; this lane owns column m=l15 ----
    const bool diag = (t0 + 128 > s0);
    const float SC = 0.18033688f;  // (1/8) * log2(e)
    float rmax = -1e30f;
#pragma unroll
    for (int fn = 0; fn < 8; ++fn)
#pragma unroll
      for (int r = 0; r < 4; ++r) {
        float v = st[fn][r] * SC;
        if (diag) {
          int tg = t0 + fn * 16 + l4 * 4 + r;
          if (tg > sgl) v = -1e30f;
        }
        st[fn][r] = v;
        rmax = fmaxf(rmax, v);
      }
    rmax = fmaxf(rmax, __shfl_xor(rmax, 16));
    rmax = fmaxf(rmax, __shfl_xor(rmax, 32));
    float mnew = fmaxf(mrow, rmax);
    float alpha = __builtin_amdgcn_exp2f(mrow - mnew);
    mrow = mnew;
    float rsum = 0.f;
#pragma unroll
    for (int fn = 0; fn < 8; ++fn)
#pragma unroll
      for (int r = 0; r < 4; ++r) {
        float p = __builtin_amdgcn_exp2f(st[fn][r] - mnew);
        st[fn][r] = p;
        rsum += p;
      }
    rsum += __shfl_xor(rsum, 16);
    rsum += __shfl_xor(rsum, 32);
    lrow = lrow * alpha + rsum;

    // alpha into O-layout (accO rows m = l4*4+r; alpha lives in lane with l15 = m)
    float aO[4];
#pragma unroll
    for (int r = 0; r < 4; ++r) aO[r] = __shfl(alpha, (lane & 48) | (l4 * 4 + r));
#pragma unroll
    for (int fd = 0; fd < 4; ++fd)
#pragma unroll
      for (int r = 0; r < 4; ++r) accO[fd][r] *= aO[r];

    __syncthreads();  // ALL waves done reading K before P^T overwrites KP

    // ---- P^T -> LDS [m][t] stride 136; lane holds 4 consecutive t per frag ----
#pragma unroll
    for (int fn = 0; fn < 8; ++fn) {
      ushort4 pk;
      pk.x = f2bf_ru(st[fn][0]);
      pk.y = f2bf_ru(st[fn][1]);
      pk.z = f2bf_ru(st[fn][2]);
      pk.w = f2bf_ru(st[fn][3]);
      *(ushort4*)&KP[(w * 16 + l15) * 136 + fn * 16 + l4 * 4] = pk;
    }
    // intra-wave DS ordering: own strip writes visible to own reads

    // ---- O += P V  (A from P^T strip, B from V^T tile) ----
#pragma unroll
    for (int ks = 0; ks < 4; ++ks) {
      bf16x8 ap = *(const bf16x8*)&KP[(w * 16 + l15) * 136 + ks * 32 + l4 * 8];
#pragma unroll
      for (int fd = 0; fd < 4; ++fd) {
        int d = fd * 16 + l15;
        bf16x8 bv = *(const bf16x8*)&Vts[d * 128 + (((ks * 4 + l4) ^ (d & 15)) * 8)];
        accO[fd] = MFMA_BF16(ap, bv, accO[fd]);
      }
    }
  }

  // ---- epilogue ----
  float lO[4];
#pragma unroll
  for (int r = 0; r < 4; ++r) lO[r] = __shfl(lrow, (lane & 48) | (l4 * 4 + r));
#pragma unroll
  for (int fd = 0; fd < 4; ++fd)
#pragma unroll
    for (int r = 0; r < 4; ++r) {
      int row = s0 + w * 16 + l4 * 4 + r;
      int col = h * 64 + fd * 16 + l15;
      Yg[(n * 2048 + row) * 512 + col] = f2bf(accO[fd][r] / lO[r]);
    }
}

extern "C" void kernel_launch(void* const* d_in, const int* in_sizes, int n_in,
                              void* d_out, int out_size, void* d_ws, size_t ws_size,
                              hipStream_t stream) {
  (void)in_sizes; (void)n_in; (void)out_size; (void)ws_size;
  const float* query = (const float*)d_in[0];
  const float* key_  = (const float*)d_in[1];
  const float* value = (const float*)d_in[2];
  // d_in[3] = attn_mask (tril) — causal, applied structurally
  const float* Wq = (const float*)d_in[4];
  const float* bq = (const float*)d_in[5];
  const float* Wk = (const float*)d_in[6];
  const float* bk = (const float*)d_in[7];
  const float* Wv = (const float*)d_in[8];
  const float* bv = (const float*)d_in[9];
  const float* Wp = (const float*)d_in[10];
  const float* bp = (const float*)d_in[11];

  char* ws = (char*)d_ws;  // 50 MB total (same as R1 footprint)
  u16* qx  = (u16*)(ws);                // 8 MB; reused as y after q-proj
  u16* kx  = (u16*)(ws + 8388608);      // 8 MB; reused as vt after k-proj
  u16* vx  = (u16*)(ws + 16777216);     // 8 MB
  u16* wqx = (u16*)(ws + 25165824);
  u16* wkx = (u16*)(ws + 25690112);
  u16* wvx = (u16*)(ws + 26214400);
  u16* wpx = (u16*)(ws + 26738688);
  u16* qp  = (u16*)(ws + 27262976);     // 8 MB
  u16* kp  = (u16*)(ws + 35651584);     // 8 MB
  u16* vp  = (u16*)(ws + 44040192);     // 8 MB
  u16* y   = qx;
  u16* vt  = kx;  // kx dead after gemm_qkv

  cast3<<<dim3(4096, 3), 256, 0, stream>>>(query, key_, value, qx, kx, vx);
  cast4<<<dim3(256, 4), 256, 0, stream>>>(Wq, Wk, Wv, Wp, wqx, wkx, wvx, wpx);

  gemm_qkv<<<dim3(12, 64), 256, 0, stream>>>(qx, kx, vx, wqx, wkx, wvx,
                                             bq, bk, bv, qp, kp, vp);
  transpose_v<<<1024, 256, 0, stream>>>(vp, vt);
  attn_kernel<<<1024, 256, 0, stream>>>(qp, kp, vt, y);
  gemm_out<<<dim3(4, 64), 256, 0, stream>>>(y, wpx, bp, (float*)d_out);
}